// Round 7
// baseline (335.860 us; speedup 1.0000x reference)
//
#include <hip/hip_runtime.h>
#include <hip/hip_fp16.h>
#include <cstdint>
#include <cstddef>

#define HID 2560
#define NH  32
#define DHD 80
#define DHP 96
#define NB  2
#define NS  2048
#define NL  512

typedef _Float16 half8_t __attribute__((ext_vector_type(8)));
typedef float f32x4_t __attribute__((ext_vector_type(4)));

__device__ __forceinline__ void gload_lds16(const __half* g, __half* l) {
  __builtin_amdgcn_global_load_lds(
      (const __attribute__((address_space(1))) unsigned int*)g,
      (__attribute__((address_space(3))) unsigned int*)l, 16, 0, 0);
}

// ---- fused: cast fp32->fp16 (6 tensors) + zero Q/K pad columns ----------
__global__ __launch_bounds__(256) void cast_all(const float* __restrict__ X,
                                                const float* __restrict__ LS,
                                                const float* __restrict__ Wq,
                                                const float* __restrict__ Wk,
                                                const float* __restrict__ Wv,
                                                const float* __restrict__ Wo,
                                                __half* __restrict__ Xh,
                                                __half* __restrict__ Lh,
                                                __half* __restrict__ Wqh,
                                                __half* __restrict__ Wkh,
                                                __half* __restrict__ Wvh,
                                                __half* __restrict__ Woh,
                                                __half* __restrict__ Qa,
                                                __half* __restrict__ Ka) {
  const int nX = NB * NS * HID / 4, nL = NB * NL * HID / 4, nW = HID * HID / 4;
  const int ncast = nX + nL + 4 * nW;
  const int qrows = NB * NH * NS, krows = NB * NH * NL;
  const int total = ncast + qrows + krows;
  for (int i = blockIdx.x * 256 + threadIdx.x; i < total; i += gridDim.x * 256) {
    if (i < ncast) {
      const float* src; __half* dst; int off;
      if (i < nX) { src = X; dst = Xh; off = i; }
      else if (i < nX + nL) { src = LS; dst = Lh; off = i - nX; }
      else {
        int j = i - nX - nL;
        int w = j / nW; off = j - w * nW;
        src = (w == 0) ? Wq : (w == 1) ? Wk : (w == 2) ? Wv : Wo;
        dst = (w == 0) ? Wqh : (w == 1) ? Wkh : (w == 2) ? Wvh : Woh;
      }
      float4 v = ((const float4*)src)[off];
      union { __half h[4]; uint2 u; } r;
      r.h[0] = __float2half(v.x);
      r.h[1] = __float2half(v.y);
      r.h[2] = __float2half(v.z);
      r.h[3] = __float2half(v.w);
      ((uint2*)dst)[off] = r.u;
    } else {
      const int j = i - ncast;
      const uint4 z = {0, 0, 0, 0};
      uint4* p = (j < qrows)
          ? (uint4*)(Qa + (size_t)j * DHP + DHD)
          : (uint4*)(Ka + (size_t)(j - qrows) * DHP + DHD);
      p[0] = z; p[1] = z;
    }
  }
}

// ============ 256x256-tile, BK=64, 8-wave core (T2+T3+T4+T5) =============
// m201-order phases: every phase's ds_reads are issued BEFORE its opening
// barrier (overlapping other waves' MFMA). Phase 0's fragment reads
// (af_lo + bf01 of tile kt) are performed at phase 3 of tile kt-1
// (read-ahead into the same registers; liveness-verified register-neutral).
// vmcnt(0) sits at ph3, draining loads issued >=2 phases earlier.
__device__ __forceinline__ void gemm256_core(const __half* A, const __half* Bt,
                                             int bm, int bn, __half* smem,
                                             f32x4_t (&acc)[8][4]) {
  const int K = HID;
  const int tid  = threadIdx.x;
  const int lane = tid & 63;
  const int wave = tid >> 6;
  const int wr = wave >> 2, wc = wave & 3;
  const int fr = lane & 15, kb = lane >> 4;

  const int sr = tid >> 3;
  const int sj = (tid & 7) ^ (sr & 7);
  const __half* gA = A  + (size_t)(bm * 256 + sr) * K + sj * 8;
  const __half* gB = Bt + (size_t)(bn * 256 + sr) * K + sj * 8;

  auto stage = [&](int h, int kt, int bank) {
    const __half* gbase = (h < 2) ? gA : gB;
    const int rbase = (h & 1) * 128;
#pragma unroll
    for (int i = 0; i < 2; ++i) {
      const __half* g = gbase + (size_t)(rbase + i * 64) * K + (size_t)kt * 64;
      __half* l = smem + bank * 32768 + (h < 2 ? 0 : 16384) + (rbase + i * 64) * 64 + tid * 8;
      gload_lds16(g, l);
    }
  };
  auto rdA = [&](int m, int kk, int bank) -> half8_t {
    const int row = wr * 128 + m * 16 + fr;
    const int off = row * 128 + ((kk * 64 + kb * 16) ^ ((fr & 7) << 4));
    return *(const half8_t*)((const char*)(smem + bank * 32768) + off);
  };
  auto rdB = [&](int n, int kk, int bank) -> half8_t {
    const int row = wc * 64 + n * 16 + fr;
    const int off = row * 128 + ((kk * 64 + kb * 16) ^ ((fr & 7) << 4));
    return *(const half8_t*)((const char*)(smem + bank * 32768 + 16384) + off);
  };

  half8_t af[4][2], bf01[2][2], bf23[2][2];

  // prologue: stage full tile kt=0 into bank 0, drain, read af(lo)+bf01
#pragma unroll
  for (int h = 0; h < 4; ++h) stage(h, 0, 0);
  asm volatile("s_waitcnt vmcnt(0)" ::: "memory");
  asm volatile("s_barrier" ::: "memory");
#pragma unroll
  for (int m = 0; m < 4; ++m)
#pragma unroll
    for (int kk = 0; kk < 2; ++kk) af[m][kk] = rdA(m, kk, 0);
#pragma unroll
  for (int n = 0; n < 2; ++n)
#pragma unroll
    for (int kk = 0; kk < 2; ++kk) bf01[n][kk] = rdB(n, kk, 0);

  const int nk = K >> 6;
  for (int kt = 0; kt < nk; ++kt) {
    const int bk = kt & 1, nb2 = bk ^ 1;
    const bool pf = (kt + 1 < nk);

    // ---- phase 0: MFMA(m0-3, n0-1); stage A half-tiles of kt+1
    if (pf) { stage(0, kt + 1, nb2); stage(1, kt + 1, nb2); }
    asm volatile("s_barrier" ::: "memory");
    __builtin_amdgcn_s_setprio(1);
#pragma unroll
    for (int m = 0; m < 4; ++m)
#pragma unroll
      for (int n = 0; n < 2; ++n)
#pragma unroll
        for (int kk = 0; kk < 2; ++kk)
          acc[m][n] = __builtin_amdgcn_mfma_f32_16x16x32_f16(af[m][kk], bf01[n][kk], acc[m][n], 0, 0, 0);
    __builtin_amdgcn_s_setprio(0);
    asm volatile("s_barrier" ::: "memory");

    // ---- phase 1: reads bf23(bk); stage B half-tiles of kt+1; MFMA(m0-3, n2-3)
#pragma unroll
    for (int n = 0; n < 2; ++n)
#pragma unroll
      for (int kk = 0; kk < 2; ++kk) bf23[n][kk] = rdB(n + 2, kk, bk);
    if (pf) { stage(2, kt + 1, nb2); stage(3, kt + 1, nb2); }
    asm volatile("s_barrier" ::: "memory");
    __builtin_amdgcn_s_setprio(1);
#pragma unroll
    for (int m = 0; m < 4; ++m)
#pragma unroll
      for (int n = 0; n < 2; ++n)
#pragma unroll
        for (int kk = 0; kk < 2; ++kk)
          acc[m][n + 2] = __builtin_amdgcn_mfma_f32_16x16x32_f16(af[m][kk], bf23[n][kk], acc[m][n + 2], 0, 0, 0);
    __builtin_amdgcn_s_setprio(0);
    asm volatile("s_barrier" ::: "memory");

    // ---- phase 2: reads af<-hi(bk); MFMA(m4-7, n0-1)
#pragma unroll
    for (int m = 0; m < 4; ++m)
#pragma unroll
      for (int kk = 0; kk < 2; ++kk) af[m][kk] = rdA(m + 4, kk, bk);
    asm volatile("s_barrier" ::: "memory");
    __builtin_amdgcn_s_setprio(1);
#pragma unroll
    for (int m = 0; m < 4; ++m)
#pragma unroll
      for (int n = 0; n < 2; ++n)
#pragma unroll
        for (int kk = 0; kk < 2; ++kk)
          acc[m + 4][n] = __builtin_amdgcn_mfma_f32_16x16x32_f16(af[m][kk], bf01[n][kk], acc[m + 4][n], 0, 0, 0);
    __builtin_amdgcn_s_setprio(0);
    asm volatile("s_barrier" ::: "memory");

    // ---- phase 3: drain kt+1 loads; MFMA(m4-7, n2-3) || read-ahead
    //      af<-lo(kt+1), bf01(kt+1) from the other bank (kt regs dead).
    if (pf) asm volatile("s_waitcnt vmcnt(0)" ::: "memory");
    asm volatile("s_barrier" ::: "memory");
    __builtin_amdgcn_s_setprio(1);
#pragma unroll
    for (int m = 0; m < 4; ++m)
#pragma unroll
      for (int n = 0; n < 2; ++n)
#pragma unroll
        for (int kk = 0; kk < 2; ++kk)
          acc[m + 4][n + 2] = __builtin_amdgcn_mfma_f32_16x16x32_f16(af[m][kk], bf23[n][kk], acc[m + 4][n + 2], 0, 0, 0);
    __builtin_amdgcn_s_setprio(0);
    if (pf) {
#pragma unroll
      for (int m = 0; m < 4; ++m)
#pragma unroll
        for (int kk = 0; kk < 2; ++kk) af[m][kk] = rdA(m, kk, nb2);
#pragma unroll
      for (int n = 0; n < 2; ++n)
#pragma unroll
        for (int kk = 0; kk < 2; ++kk) bf01[n][kk] = rdB(n, kk, nb2);
    }
    asm volatile("s_barrier" ::: "memory");
  }
}

// -------- fused QKV projection: 240 blocks = 160 Q + 40 K + 40 V ---------
__global__ __launch_bounds__(512) void fused_qkv(const __half* __restrict__ X,
                                                 const __half* __restrict__ L,
                                                 const __half* __restrict__ Wq,
                                                 const __half* __restrict__ Wk,
                                                 const __half* __restrict__ Wv,
                                                 __half* __restrict__ Qa,
                                                 __half* __restrict__ Ka,
                                                 __half* __restrict__ Va) {
  __shared__ __half smem[2 * 32768];
  int wg = blockIdx.x;                       // 240 = 8 XCD * 30
  wg = (wg & 7) * 30 + (wg >> 3);            // bijective XCD swizzle

  int mode, bm, bn;
  const __half *A, *B;
  if (wg < 160)      { mode = 0; A = X; B = Wq; bm = wg / 10;        bn = wg - bm * 10; }
  else if (wg < 200) { mode = 1; A = L; B = Wk; bm = (wg - 160) / 10; bn = (wg - 160) - bm * 10; }
  else               { mode = 2; A = L; B = Wv; bm = (wg - 200) / 10; bn = (wg - 200) - bm * 10; }

  f32x4_t acc[8][4] = {};
  gemm256_core(A, B, bm, bn, smem, acc);

  const int lane = threadIdx.x & 63, wave = threadIdx.x >> 6;
  const int wr = wave >> 2, wc = wave & 3;
  const int fr = lane & 15, kb = lane >> 4;

#pragma unroll
  for (int m = 0; m < 8; ++m)
#pragma unroll
    for (int n = 0; n < 4; ++n)
#pragma unroll
      for (int r = 0; r < 4; ++r) {
        const int row = bm * 256 + wr * 128 + m * 16 + kb * 4 + r;
        const int col = bn * 256 + wc * 64 + n * 16 + fr;
        const float v = acc[m][n][r];
        const int h = col / DHD, d = col - h * DHD;
        if (mode == 0) {
          const int b = row >> 11, s = row & 2047;
          Qa[(((size_t)(b * NH + h)) * NS + s) * DHP + d] =
              __float2half(v * 0.11180339887498949f);     // 1/sqrt(80) folded
        } else if (mode == 1) {
          const int b = row >> 9, l = row & 511;
          Ka[(((size_t)(b * NH + h)) * NL + l) * DHP + d] = __float2half(v);
        } else {
          const int b = row >> 9, l = row & 511;
          Va[(((size_t)(b * NH + h)) * DHP + d) * NL + l] = __float2half(v);
        }
      }
}

// -------- O projection: out = gate * (AO x Wo^T), fp32, 160 blocks -------
__global__ __launch_bounds__(512) void gemm256_o(const __half* __restrict__ A,
                                                 const __half* __restrict__ Bt,
                                                 float* __restrict__ out,
                                                 const float* __restrict__ gate_p) {
  __shared__ __half smem[2 * 32768];
  int wg = blockIdx.x;                       // 160 = 8 XCD * 20
  wg = (wg & 7) * 20 + (wg >> 3);
  const int bm = wg / 10, bn = wg - bm * 10;

  f32x4_t acc[8][4] = {};
  gemm256_core(A, Bt, bm, bn, smem, acc);

  const float gate = tanhf(gate_p[0]);
  const int lane = threadIdx.x & 63, wave = threadIdx.x >> 6;
  const int wr = wave >> 2, wc = wave & 3;
  const int fr = lane & 15, kb = lane >> 4;

#pragma unroll
  for (int m = 0; m < 8; ++m)
#pragma unroll
    for (int n = 0; n < 4; ++n)
#pragma unroll
      for (int r = 0; r < 4; ++r) {
        const int row = bm * 256 + wr * 128 + m * 16 + kb * 4 + r;
        const int col = bn * 256 + wc * 64 + n * 16 + fr;
        out[(size_t)row * HID + col] = gate * acc[m][n][r];
      }
}

// ------- attention: K/V staged per-block in LDS (64-key chunks) ----------
__global__ __launch_bounds__(256) void attn_kernel(const __half* __restrict__ Q,
                                                   const __half* __restrict__ Kt,
                                                   const __half* __restrict__ Vt,
                                                   float* __restrict__ P,
                                                   __half* __restrict__ AO) {
  __shared__ __half Pl[4 * 16 * 520];
  __shared__ __half KV[6144];
  const int tid = threadIdx.x;
  const int lane = tid & 63, wave = tid >> 6;
  const int fr = lane & 15, kb = lane >> 4;
  const int bh = blockIdx.y;
  const int r0 = blockIdx.x * 64 + wave * 16;

  const __half* Qb = Q  + ((size_t)bh * NS + r0) * DHP;
  const __half* Kb = Kt + (size_t)bh * NL * DHP;
  const __half* Vb = Vt + (size_t)bh * DHP * NL;

  half8_t aq[3];
#pragma unroll
  for (int kk = 0; kk < 3; ++kk)
    aq[kk] = *(const half8_t*)(Qb + (size_t)fr * DHP + kk * 32 + kb * 8);

  f32x4_t scr[32];

  for (int c = 0; c < 8; ++c) {
#pragma unroll
    for (int i = 0; i < 3; ++i) {
      const int s = (wave * 3 + i) * 64 + lane;
      gload_lds16(Kb + (size_t)c * 64 * DHP + s * 8, KV + s * 8);
    }
    __syncthreads();
#pragma unroll
    for (int ntl = 0; ntl < 4; ++ntl) {
      f32x4_t a = {};
#pragma unroll
      for (int kk = 0; kk < 3; ++kk) {
        half8_t bfv = *(const half8_t*)(KV + (ntl * 16 + fr) * DHP + kk * 32 + kb * 8);
        a = __builtin_amdgcn_mfma_f32_16x16x32_f16(aq[kk], bfv, a, 0, 0, 0);
      }
      scr[c * 4 + ntl] = a;
    }
    __syncthreads();
  }

  __half* Plw = Pl + wave * (16 * 520);
#pragma unroll
  for (int r = 0; r < 4; ++r) {
    float m = -1e30f;
#pragma unroll
    for (int nt = 0; nt < 32; ++nt) m = fmaxf(m, scr[nt][r]);
#pragma unroll
    for (int d = 1; d < 16; d <<= 1) m = fmaxf(m, __shfl_xor(m, d));
    float s = 0.f;
#pragma unroll
    for (int nt = 0; nt < 32; ++nt) {
      float p = __expf(scr[nt][r] - m);
      scr[nt][r] = p;
      s += p;
    }
#pragma unroll
    for (int d = 1; d < 16; d <<= 1) s += __shfl_xor(s, d);
    const float iv = 1.f / s;
    const int srow = r0 + kb * 4 + r;
    float* Pr = P + ((size_t)bh * NS + srow) * NL;
#pragma unroll
    for (int nt = 0; nt < 32; ++nt) {
      float p = scr[nt][r] * iv;
      Pr[nt * 16 + fr] = p;
      Plw[(kb * 4 + r) * 520 + nt * 16 + fr] = __float2half(p);
    }
  }

  f32x4_t oc[5] = {};
  for (int c = 0; c < 8; ++c) {
#pragma unroll
    for (int i = 0; i < 3; ++i) {
      const int s = (wave * 3 + i) * 64 + lane;
      int row = s / 9;
      int col = s - row * 9;
      if (row > 79) row = 79;
      if (col > 7) col = 7;
      gload_lds16(Vb + (size_t)row * NL + c * 64 + col * 8, KV + s * 8);
    }
    __syncthreads();
#pragma unroll
    for (int k0l = 0; k0l < 2; ++k0l) {
      half8_t ap = *(const half8_t*)(Plw + fr * 520 + (c * 2 + k0l) * 32 + kb * 8);
#pragma unroll
      for (int n = 0; n < 5; ++n) {
        half8_t bv = *(const half8_t*)(KV + (n * 16 + fr) * 72 + k0l * 32 + kb * 8);
        oc[n] = __builtin_amdgcn_mfma_f32_16x16x32_f16(ap, bv, oc[n], 0, 0, 0);
      }
    }
    __syncthreads();
  }

  const int b = bh >> 5, h = bh & 31;
#pragma unroll
  for (int n = 0; n < 5; ++n)
#pragma unroll
    for (int r = 0; r < 4; ++r) {
      const int srow = r0 + kb * 4 + r;
      AO[((size_t)b * NS + srow) * HID + h * DHD + n * 16 + fr] = __float2half(oc[n][r]);
    }
}

extern "C" void kernel_launch(void* const* d_in, const int* in_sizes, int n_in,
                              void* d_out, int out_size, void* d_ws, size_t ws_size,
                              hipStream_t stream) {
  const float* X  = (const float*)d_in[0];
  const float* LS = (const float*)d_in[1];
  const float* Wq = (const float*)d_in[2];
  const float* Wk = (const float*)d_in[3];
  const float* Wv = (const float*)d_in[4];
  const float* Wo = (const float*)d_in[5];
  const float* gp = (const float*)d_in[6];
  float* out  = (float*)d_out;
  float* Pout = out + (size_t)NB * NS * HID;

  char* w = (char*)d_ws;
  auto alloc = [&](size_t bytes) {
    char* p = w;
    w += (bytes + 255) & ~(size_t)255;
    return p;
  };
  __half* Xh  = (__half*)alloc((size_t)NB * NS * HID * 2);
  __half* Lh  = (__half*)alloc((size_t)NB * NL * HID * 2);
  __half* Wqh = (__half*)alloc((size_t)HID * HID * 2);
  __half* Wkh = (__half*)alloc((size_t)HID * HID * 2);
  __half* Wvh = (__half*)alloc((size_t)HID * HID * 2);
  __half* Woh = (__half*)alloc((size_t)HID * HID * 2);
  __half* Qa  = (__half*)alloc((size_t)NB * NH * NS * DHP * 2);
  __half* Ka  = (__half*)alloc((size_t)NB * NH * NL * DHP * 2);
  __half* Va  = (__half*)alloc((size_t)NB * NH * DHP * NL * 2);
  (void)alloc(4096);                     // guard region after Va
  __half* AOh = Xh;  // Xh dead after QKV projection

  cast_all<<<dim3(2048), dim3(256), 0, stream>>>(X, LS, Wq, Wk, Wv, Wo,
                                                 Xh, Lh, Wqh, Wkh, Wvh, Woh,
                                                 Qa, Ka);
  fused_qkv<<<dim3(240), dim3(512), 0, stream>>>(Xh, Lh, Wqh, Wkh, Wvh, Qa, Ka, Va);
  attn_kernel<<<dim3(NS / 64, NB * NH), dim3(256), 0, stream>>>(
      Qa, Ka, Va, Pout, AOh);
  gemm256_o<<<dim3(160), dim3(512), 0, stream>>>(AOh, Woh, out, gp);
}

// Round 8
// 305.233 us; speedup vs baseline: 1.1003x; 1.1003x over previous
//
#include <hip/hip_runtime.h>
#include <hip/hip_fp16.h>
#include <cstdint>
#include <cstddef>

#define HID 2560
#define NH  32
#define DHD 80
#define DHP 96
#define NB  2
#define NS  2048
#define NL  512

typedef _Float16 half8_t __attribute__((ext_vector_type(8)));
typedef float f32x4_t __attribute__((ext_vector_type(4)));

__device__ __forceinline__ void gload_lds16(const __half* g, __half* l) {
  __builtin_amdgcn_global_load_lds(
      (const __attribute__((address_space(1))) unsigned int*)g,
      (__attribute__((address_space(3))) unsigned int*)l, 16, 0, 0);
}

// ---- fused: cast fp32->fp16 (6 tensors) + zero Q/K pad columns ----------
__global__ __launch_bounds__(256) void cast_all(const float* __restrict__ X,
                                                const float* __restrict__ LS,
                                                const float* __restrict__ Wq,
                                                const float* __restrict__ Wk,
                                                const float* __restrict__ Wv,
                                                const float* __restrict__ Wo,
                                                __half* __restrict__ Xh,
                                                __half* __restrict__ Lh,
                                                __half* __restrict__ Wqh,
                                                __half* __restrict__ Wkh,
                                                __half* __restrict__ Wvh,
                                                __half* __restrict__ Woh,
                                                __half* __restrict__ Qa,
                                                __half* __restrict__ Ka) {
  const int nX = NB * NS * HID / 4, nL = NB * NL * HID / 4, nW = HID * HID / 4;
  const int ncast = nX + nL + 4 * nW;
  const int qrows = NB * NH * NS, krows = NB * NH * NL;
  const int total = ncast + qrows + krows;
  for (int i = blockIdx.x * 256 + threadIdx.x; i < total; i += gridDim.x * 256) {
    if (i < ncast) {
      const float* src; __half* dst; int off;
      if (i < nX) { src = X; dst = Xh; off = i; }
      else if (i < nX + nL) { src = LS; dst = Lh; off = i - nX; }
      else {
        int j = i - nX - nL;
        int w = j / nW; off = j - w * nW;
        src = (w == 0) ? Wq : (w == 1) ? Wk : (w == 2) ? Wv : Wo;
        dst = (w == 0) ? Wqh : (w == 1) ? Wkh : (w == 2) ? Wvh : Woh;
      }
      float4 v = ((const float4*)src)[off];
      union { __half h[4]; uint2 u; } r;
      r.h[0] = __float2half(v.x);
      r.h[1] = __float2half(v.y);
      r.h[2] = __float2half(v.z);
      r.h[3] = __float2half(v.w);
      ((uint2*)dst)[off] = r.u;
    } else {
      const int j = i - ncast;
      const uint4 z = {0, 0, 0, 0};
      uint4* p = (j < qrows)
          ? (uint4*)(Qa + (size_t)j * DHP + DHD)
          : (uint4*)(Ka + (size_t)(j - qrows) * DHP + DHD);
      p[0] = z; p[1] = z;
    }
  }
}

// ============ 256x256-tile, BK=64, 8-wave core (round-6 proven version) ==
// Staging front-loaded: phase0 issues half-tiles 0+1 of kt+1, phase1 issues 2,
// phase2 issues 3, phase3 none; vmcnt(4) at phase0 keeps the 4 just-issued
// next-tile loads in flight (T3/T4); setprio around MFMA clusters (T5);
// XOR swizzle byte^=(row&7)<<4 via pre-swizzled source + swizzled read (T2).
__device__ __forceinline__ void gemm256_core(const __half* A, const __half* Bt,
                                             int bm, int bn, __half* smem,
                                             f32x4_t (&acc)[8][4]) {
  const int K = HID;
  const int tid  = threadIdx.x;
  const int lane = tid & 63;
  const int wave = tid >> 6;
  const int wr = wave >> 2, wc = wave & 3;
  const int fr = lane & 15, kb = lane >> 4;

  const int sr = tid >> 3;
  const int sj = (tid & 7) ^ (sr & 7);
  const __half* gA = A  + (size_t)(bm * 256 + sr) * K + sj * 8;
  const __half* gB = Bt + (size_t)(bn * 256 + sr) * K + sj * 8;

  auto stage = [&](int h, int kt, int bank) {
    const __half* gbase = (h < 2) ? gA : gB;
    const int rbase = (h & 1) * 128;
#pragma unroll
    for (int i = 0; i < 2; ++i) {
      const __half* g = gbase + (size_t)(rbase + i * 64) * K + (size_t)kt * 64;
      __half* l = smem + bank * 32768 + (h < 2 ? 0 : 16384) + (rbase + i * 64) * 64 + tid * 8;
      gload_lds16(g, l);
    }
  };
  auto rdA = [&](int m, int kk, int bank) -> half8_t {
    const int row = wr * 128 + m * 16 + fr;
    const int off = row * 128 + ((kk * 64 + kb * 16) ^ ((fr & 7) << 4));
    return *(const half8_t*)((const char*)(smem + bank * 32768) + off);
  };
  auto rdB = [&](int n, int kk, int bank) -> half8_t {
    const int row = wc * 64 + n * 16 + fr;
    const int off = row * 128 + ((kk * 64 + kb * 16) ^ ((fr & 7) << 4));
    return *(const half8_t*)((const char*)(smem + bank * 32768 + 16384) + off);
  };

  half8_t af[4][2], bf[4][2];

#pragma unroll
  for (int h = 0; h < 4; ++h) stage(h, 0, 0);

  const int nk = K >> 6;
  for (int kt = 0; kt < nk; ++kt) {
    const int bk = kt & 1, nb2 = bk ^ 1;
    const bool pf = (kt + 1 < nk);

    // ---- phase 0: (m0-3, n0-1); issue half-tiles 0+1 of kt+1
    if (pf) { stage(0, kt + 1, nb2); stage(1, kt + 1, nb2); }
    if (pf) asm volatile("s_waitcnt vmcnt(4)" ::: "memory");
    else    asm volatile("s_waitcnt vmcnt(0)" ::: "memory");
    asm volatile("s_barrier" ::: "memory");
#pragma unroll
    for (int m = 0; m < 4; ++m)
#pragma unroll
      for (int kk = 0; kk < 2; ++kk) af[m][kk] = rdA(m, kk, bk);
#pragma unroll
    for (int n = 0; n < 2; ++n)
#pragma unroll
      for (int kk = 0; kk < 2; ++kk) bf[n][kk] = rdB(n, kk, bk);
    __builtin_amdgcn_s_setprio(1);
#pragma unroll
    for (int m = 0; m < 4; ++m)
#pragma unroll
      for (int n = 0; n < 2; ++n)
#pragma unroll
        for (int kk = 0; kk < 2; ++kk)
          acc[m][n] = __builtin_amdgcn_mfma_f32_16x16x32_f16(af[m][kk], bf[n][kk], acc[m][n], 0, 0, 0);
    __builtin_amdgcn_s_setprio(0);
    asm volatile("s_barrier" ::: "memory");

    // ---- phase 1: (m0-3, n2-3); issue half-tile 2
#pragma unroll
    for (int n = 2; n < 4; ++n)
#pragma unroll
      for (int kk = 0; kk < 2; ++kk) bf[n][kk] = rdB(n, kk, bk);
    if (pf) stage(2, kt + 1, nb2);
    asm volatile("s_barrier" ::: "memory");
    __builtin_amdgcn_s_setprio(1);
#pragma unroll
    for (int m = 0; m < 4; ++m)
#pragma unroll
      for (int n = 2; n < 4; ++n)
#pragma unroll
        for (int kk = 0; kk < 2; ++kk)
          acc[m][n] = __builtin_amdgcn_mfma_f32_16x16x32_f16(af[m][kk], bf[n][kk], acc[m][n], 0, 0, 0);
    __builtin_amdgcn_s_setprio(0);
    asm volatile("s_barrier" ::: "memory");

    // ---- phase 2: (m4-7, n2-3); issue half-tile 3
#pragma unroll
    for (int m = 0; m < 4; ++m)
#pragma unroll
      for (int kk = 0; kk < 2; ++kk) af[m][kk] = rdA(m + 4, kk, bk);
    if (pf) stage(3, kt + 1, nb2);
    asm volatile("s_barrier" ::: "memory");
    __builtin_amdgcn_s_setprio(1);
#pragma unroll
    for (int m = 0; m < 4; ++m)
#pragma unroll
      for (int n = 2; n < 4; ++n)
#pragma unroll
        for (int kk = 0; kk < 2; ++kk)
          acc[m + 4][n] = __builtin_amdgcn_mfma_f32_16x16x32_f16(af[m][kk], bf[n][kk], acc[m + 4][n], 0, 0, 0);
    __builtin_amdgcn_s_setprio(0);
    asm volatile("s_barrier" ::: "memory");

    // ---- phase 3: (m4-7, n0-1); no staging
    asm volatile("s_barrier" ::: "memory");
    __builtin_amdgcn_s_setprio(1);
#pragma unroll
    for (int m = 0; m < 4; ++m)
#pragma unroll
      for (int n = 0; n < 2; ++n)
#pragma unroll
        for (int kk = 0; kk < 2; ++kk)
          acc[m + 4][n] = __builtin_amdgcn_mfma_f32_16x16x32_f16(af[m][kk], bf[n][kk], acc[m + 4][n], 0, 0, 0);
    __builtin_amdgcn_s_setprio(0);
    asm volatile("s_barrier" ::: "memory");
  }
}

// -------- fused QKV projection: 240 blocks = 160 Q + 40 K + 40 V ---------
__global__ __launch_bounds__(512) void fused_qkv(const __half* __restrict__ X,
                                                 const __half* __restrict__ L,
                                                 const __half* __restrict__ Wq,
                                                 const __half* __restrict__ Wk,
                                                 const __half* __restrict__ Wv,
                                                 __half* __restrict__ Qa,
                                                 __half* __restrict__ Ka,
                                                 __half* __restrict__ Va) {
  __shared__ __half smem[2 * 32768];
  int wg = blockIdx.x;                       // 240 = 8 XCD * 30
  wg = (wg & 7) * 30 + (wg >> 3);            // bijective XCD swizzle

  int mode, bm, bn;
  const __half *A, *B;
  if (wg < 160)      { mode = 0; A = X; B = Wq; bm = wg / 10;        bn = wg - bm * 10; }
  else if (wg < 200) { mode = 1; A = L; B = Wk; bm = (wg - 160) / 10; bn = (wg - 160) - bm * 10; }
  else               { mode = 2; A = L; B = Wv; bm = (wg - 200) / 10; bn = (wg - 200) - bm * 10; }

  f32x4_t acc[8][4] = {};
  gemm256_core(A, B, bm, bn, smem, acc);

  const int lane = threadIdx.x & 63, wave = threadIdx.x >> 6;
  const int wr = wave >> 2, wc = wave & 3;
  const int fr = lane & 15, kb = lane >> 4;

#pragma unroll
  for (int m = 0; m < 8; ++m)
#pragma unroll
    for (int n = 0; n < 4; ++n)
#pragma unroll
      for (int r = 0; r < 4; ++r) {
        const int row = bm * 256 + wr * 128 + m * 16 + kb * 4 + r;
        const int col = bn * 256 + wc * 64 + n * 16 + fr;
        const float v = acc[m][n][r];
        const int h = col / DHD, d = col - h * DHD;
        if (mode == 0) {
          const int b = row >> 11, s = row & 2047;
          Qa[(((size_t)(b * NH + h)) * NS + s) * DHP + d] =
              __float2half(v * 0.11180339887498949f);     // 1/sqrt(80) folded
        } else if (mode == 1) {
          const int b = row >> 9, l = row & 511;
          Ka[(((size_t)(b * NH + h)) * NL + l) * DHP + d] = __float2half(v);
        } else {
          const int b = row >> 9, l = row & 511;
          Va[(((size_t)(b * NH + h)) * DHP + d) * NL + l] = __float2half(v);
        }
      }
}

// -------- O projection: out = gate * (AO x Wo^T), fp32, 160 blocks -------
__global__ __launch_bounds__(512) void gemm256_o(const __half* __restrict__ A,
                                                 const __half* __restrict__ Bt,
                                                 float* __restrict__ out,
                                                 const float* __restrict__ gate_p) {
  __shared__ __half smem[2 * 32768];
  int wg = blockIdx.x;                       // 160 = 8 XCD * 20
  wg = (wg & 7) * 20 + (wg >> 3);
  const int bm = wg / 10, bn = wg - bm * 10;

  f32x4_t acc[8][4] = {};
  gemm256_core(A, Bt, bm, bn, smem, acc);

  const float gate = tanhf(gate_p[0]);
  const int lane = threadIdx.x & 63, wave = threadIdx.x >> 6;
  const int wr = wave >> 2, wc = wave & 3;
  const int fr = lane & 15, kb = lane >> 4;

#pragma unroll
  for (int m = 0; m < 8; ++m)
#pragma unroll
    for (int n = 0; n < 4; ++n)
#pragma unroll
      for (int r = 0; r < 4; ++r) {
        const int row = bm * 256 + wr * 128 + m * 16 + kb * 4 + r;
        const int col = bn * 256 + wc * 64 + n * 16 + fr;
        __builtin_nontemporal_store(gate * acc[m][n][r],
                                    &out[(size_t)row * HID + col]);
      }
}

// ------- attention: K/V staged per-block in LDS (64-key chunks) ----------
// P global writes DEFERRED until after PV so the PV-loop __syncthreads
// (vmcnt(0) drains) never wait on the 64KB/block P-store stream.
// V chunk 0 prefetched before softmax (latency hidden under exp/reduce).
__global__ __launch_bounds__(256, 2) void attn_kernel(const __half* __restrict__ Q,
                                                      const __half* __restrict__ Kt,
                                                      const __half* __restrict__ Vt,
                                                      float* __restrict__ P,
                                                      __half* __restrict__ AO) {
  __shared__ __half Pl[4 * 16 * 520];
  __shared__ __half KV[6144];
  const int tid = threadIdx.x;
  const int lane = tid & 63, wave = tid >> 6;
  const int fr = lane & 15, kb = lane >> 4;
  const int bh = blockIdx.y;
  const int r0 = blockIdx.x * 64 + wave * 16;

  const __half* Qb = Q  + ((size_t)bh * NS + r0) * DHP;
  const __half* Kb = Kt + (size_t)bh * NL * DHP;
  const __half* Vb = Vt + (size_t)bh * DHP * NL;

  half8_t aq[3];
#pragma unroll
  for (int kk = 0; kk < 3; ++kk)
    aq[kk] = *(const half8_t*)(Qb + (size_t)fr * DHP + kk * 32 + kb * 8);

  f32x4_t scr[32];

  // ---- QK^T: 8 chunks of 64 keys staged in LDS ----
  for (int c = 0; c < 8; ++c) {
#pragma unroll
    for (int i = 0; i < 3; ++i) {
      const int s = (wave * 3 + i) * 64 + lane;
      gload_lds16(Kb + (size_t)c * 64 * DHP + s * 8, KV + s * 8);
    }
    __syncthreads();
#pragma unroll
    for (int ntl = 0; ntl < 4; ++ntl) {
      f32x4_t a = {};
#pragma unroll
      for (int kk = 0; kk < 3; ++kk) {
        half8_t bfv = *(const half8_t*)(KV + (ntl * 16 + fr) * DHP + kk * 32 + kb * 8);
        a = __builtin_amdgcn_mfma_f32_16x16x32_f16(aq[kk], bfv, a, 0, 0, 0);
      }
      scr[c * 4 + ntl] = a;
    }
    __syncthreads();
  }

  // ---- prefetch V chunk 0 (hides under softmax; drained by first PV sync)
#pragma unroll
  for (int i = 0; i < 3; ++i) {
    const int s = (wave * 3 + i) * 64 + lane;
    int row = s / 9;
    int col = s - row * 9;
    if (row > 79) row = 79;
    if (col > 7) col = 7;
    gload_lds16(Vb + (size_t)row * NL + col * 8, KV + s * 8);
  }

  // ---- softmax (exact), normalized p kept in scr; fp16 copy to LDS only
  __half* Plw = Pl + wave * (16 * 520);
#pragma unroll
  for (int r = 0; r < 4; ++r) {
    float m = -1e30f;
#pragma unroll
    for (int nt = 0; nt < 32; ++nt) m = fmaxf(m, scr[nt][r]);
#pragma unroll
    for (int d = 1; d < 16; d <<= 1) m = fmaxf(m, __shfl_xor(m, d));
    float s = 0.f;
#pragma unroll
    for (int nt = 0; nt < 32; ++nt) {
      float p = __expf(scr[nt][r] - m);
      scr[nt][r] = p;
      s += p;
    }
#pragma unroll
    for (int d = 1; d < 16; d <<= 1) s += __shfl_xor(s, d);
    const float iv = 1.f / s;
#pragma unroll
    for (int nt = 0; nt < 32; ++nt) {
      float p = scr[nt][r] * iv;
      scr[nt][r] = p;
      Plw[(kb * 4 + r) * 520 + nt * 16 + fr] = __float2half(p);
    }
  }

  // ---- PV: 8 chunks; chunk 0 already in flight
  f32x4_t oc[5] = {};
  for (int c = 0; c < 8; ++c) {
    if (c > 0) {
#pragma unroll
      for (int i = 0; i < 3; ++i) {
        const int s = (wave * 3 + i) * 64 + lane;
        int row = s / 9;
        int col = s - row * 9;
        if (row > 79) row = 79;
        if (col > 7) col = 7;
        gload_lds16(Vb + (size_t)row * NL + c * 64 + col * 8, KV + s * 8);
      }
    }
    __syncthreads();
#pragma unroll
    for (int k0l = 0; k0l < 2; ++k0l) {
      half8_t ap = *(const half8_t*)(Plw + fr * 520 + (c * 2 + k0l) * 32 + kb * 8);
#pragma unroll
      for (int n = 0; n < 5; ++n) {
        half8_t bv = *(const half8_t*)(KV + (n * 16 + fr) * 72 + k0l * 32 + kb * 8);
        oc[n] = __builtin_amdgcn_mfma_f32_16x16x32_f16(ap, bv, oc[n], 0, 0, 0);
      }
    }
    __syncthreads();
  }

  // ---- epilogue: AO (re-read by O-proj: cached) + P (streaming: nontemporal)
  const int b = bh >> 5, h = bh & 31;
#pragma unroll
  for (int n = 0; n < 5; ++n)
#pragma unroll
    for (int r = 0; r < 4; ++r) {
      const int srow = r0 + kb * 4 + r;
      AO[((size_t)b * NS + srow) * HID + h * DHD + n * 16 + fr] = __float2half(oc[n][r]);
    }
#pragma unroll
  for (int r = 0; r < 4; ++r) {
    const int srow = r0 + kb * 4 + r;
    float* Pr = P + ((size_t)bh * NS + srow) * NL;
#pragma unroll
    for (int nt = 0; nt < 32; ++nt)
      __builtin_nontemporal_store(scr[nt][r], &Pr[nt * 16 + fr]);
  }
}

extern "C" void kernel_launch(void* const* d_in, const int* in_sizes, int n_in,
                              void* d_out, int out_size, void* d_ws, size_t ws_size,
                              hipStream_t stream) {
  const float* X  = (const float*)d_in[0];
  const float* LS = (const float*)d_in[1];
  const float* Wq = (const float*)d_in[2];
  const float* Wk = (const float*)d_in[3];
  const float* Wv = (const float*)d_in[4];
  const float* Wo = (const float*)d_in[5];
  const float* gp = (const float*)d_in[6];
  float* out  = (float*)d_out;
  float* Pout = out + (size_t)NB * NS * HID;

  char* w = (char*)d_ws;
  auto alloc = [&](size_t bytes) {
    char* p = w;
    w += (bytes + 255) & ~(size_t)255;
    return p;
  };
  __half* Xh  = (__half*)alloc((size_t)NB * NS * HID * 2);
  __half* Lh  = (__half*)alloc((size_t)NB * NL * HID * 2);
  __half* Wqh = (__half*)alloc((size_t)HID * HID * 2);
  __half* Wkh = (__half*)alloc((size_t)HID * HID * 2);
  __half* Wvh = (__half*)alloc((size_t)HID * HID * 2);
  __half* Woh = (__half*)alloc((size_t)HID * HID * 2);
  __half* Qa  = (__half*)alloc((size_t)NB * NH * NS * DHP * 2);
  __half* Ka  = (__half*)alloc((size_t)NB * NH * NL * DHP * 2);
  __half* Va  = (__half*)alloc((size_t)NB * NH * DHP * NL * 2);
  (void)alloc(4096);                     // guard region after Va
  __half* AOh = Xh;  // Xh dead after QKV projection

  cast_all<<<dim3(2048), dim3(256), 0, stream>>>(X, LS, Wq, Wk, Wv, Wo,
                                                 Xh, Lh, Wqh, Wkh, Wvh, Woh,
                                                 Qa, Ka);
  fused_qkv<<<dim3(240), dim3(512), 0, stream>>>(Xh, Lh, Wqh, Wkh, Wvh, Qa, Ka, Va);
  attn_kernel<<<dim3(NS / 64, NB * NH), dim3(256), 0, stream>>>(
      Qa, Ka, Va, Pout, AOh);
  gemm256_o<<<dim3(160), dim3(512), 0, stream>>>(AOh, Woh, out, gp);
}

// Round 9
// 292.193 us; speedup vs baseline: 1.1494x; 1.0446x over previous
//
#include <hip/hip_runtime.h>
#include <hip/hip_fp16.h>
#include <cstdint>
#include <cstddef>

#define HID 2560
#define NH  32
#define DHD 80
#define DHP 96
#define NB  2
#define NS  2048
#define NL  512

typedef _Float16 half8_t __attribute__((ext_vector_type(8)));
typedef float f32x4_t __attribute__((ext_vector_type(4)));

__device__ __forceinline__ void gload_lds16(const __half* g, __half* l) {
  __builtin_amdgcn_global_load_lds(
      (const __attribute__((address_space(1))) unsigned int*)g,
      (__attribute__((address_space(3))) unsigned int*)l, 16, 0, 0);
}

// ---- fused: cast fp32->fp16 (6 tensors) + zero Q/K pad columns ----------
__global__ __launch_bounds__(256) void cast_all(const float* __restrict__ X,
                                                const float* __restrict__ LS,
                                                const float* __restrict__ Wq,
                                                const float* __restrict__ Wk,
                                                const float* __restrict__ Wv,
                                                const float* __restrict__ Wo,
                                                __half* __restrict__ Xh,
                                                __half* __restrict__ Lh,
                                                __half* __restrict__ Wqh,
                                                __half* __restrict__ Wkh,
                                                __half* __restrict__ Wvh,
                                                __half* __restrict__ Woh,
                                                __half* __restrict__ Qa,
                                                __half* __restrict__ Ka) {
  const int nX = NB * NS * HID / 4, nL = NB * NL * HID / 4, nW = HID * HID / 4;
  const int ncast = nX + nL + 4 * nW;
  const int qrows = NB * NH * NS, krows = NB * NH * NL;
  const int total = ncast + qrows + krows;
  for (int i = blockIdx.x * 256 + threadIdx.x; i < total; i += gridDim.x * 256) {
    if (i < ncast) {
      const float* src; __half* dst; int off;
      if (i < nX) { src = X; dst = Xh; off = i; }
      else if (i < nX + nL) { src = LS; dst = Lh; off = i - nX; }
      else {
        int j = i - nX - nL;
        int w = j / nW; off = j - w * nW;
        src = (w == 0) ? Wq : (w == 1) ? Wk : (w == 2) ? Wv : Wo;
        dst = (w == 0) ? Wqh : (w == 1) ? Wkh : (w == 2) ? Wvh : Woh;
      }
      float4 v = ((const float4*)src)[off];
      union { __half h[4]; uint2 u; } r;
      r.h[0] = __float2half(v.x);
      r.h[1] = __float2half(v.y);
      r.h[2] = __float2half(v.z);
      r.h[3] = __float2half(v.w);
      ((uint2*)dst)[off] = r.u;
    } else {
      const int j = i - ncast;
      const uint4 z = {0, 0, 0, 0};
      uint4* p = (j < qrows)
          ? (uint4*)(Qa + (size_t)j * DHP + DHD)
          : (uint4*)(Ka + (size_t)(j - qrows) * DHP + DHD);
      p[0] = z; p[1] = z;
    }
  }
}

// ============ 256x256-tile, BK=64, 8-wave core (round-6 proven version) ==
__device__ __forceinline__ void gemm256_core(const __half* A, const __half* Bt,
                                             int bm, int bn, __half* smem,
                                             f32x4_t (&acc)[8][4]) {
  const int K = HID;
  const int tid  = threadIdx.x;
  const int lane = tid & 63;
  const int wave = tid >> 6;
  const int wr = wave >> 2, wc = wave & 3;
  const int fr = lane & 15, kb = lane >> 4;

  const int sr = tid >> 3;
  const int sj = (tid & 7) ^ (sr & 7);
  const __half* gA = A  + (size_t)(bm * 256 + sr) * K + sj * 8;
  const __half* gB = Bt + (size_t)(bn * 256 + sr) * K + sj * 8;

  auto stage = [&](int h, int kt, int bank) {
    const __half* gbase = (h < 2) ? gA : gB;
    const int rbase = (h & 1) * 128;
#pragma unroll
    for (int i = 0; i < 2; ++i) {
      const __half* g = gbase + (size_t)(rbase + i * 64) * K + (size_t)kt * 64;
      __half* l = smem + bank * 32768 + (h < 2 ? 0 : 16384) + (rbase + i * 64) * 64 + tid * 8;
      gload_lds16(g, l);
    }
  };
  auto rdA = [&](int m, int kk, int bank) -> half8_t {
    const int row = wr * 128 + m * 16 + fr;
    const int off = row * 128 + ((kk * 64 + kb * 16) ^ ((fr & 7) << 4));
    return *(const half8_t*)((const char*)(smem + bank * 32768) + off);
  };
  auto rdB = [&](int n, int kk, int bank) -> half8_t {
    const int row = wc * 64 + n * 16 + fr;
    const int off = row * 128 + ((kk * 64 + kb * 16) ^ ((fr & 7) << 4));
    return *(const half8_t*)((const char*)(smem + bank * 32768 + 16384) + off);
  };

  half8_t af[4][2], bf[4][2];

#pragma unroll
  for (int h = 0; h < 4; ++h) stage(h, 0, 0);

  const int nk = K >> 6;
  for (int kt = 0; kt < nk; ++kt) {
    const int bk = kt & 1, nb2 = bk ^ 1;
    const bool pf = (kt + 1 < nk);

    if (pf) { stage(0, kt + 1, nb2); stage(1, kt + 1, nb2); }
    if (pf) asm volatile("s_waitcnt vmcnt(4)" ::: "memory");
    else    asm volatile("s_waitcnt vmcnt(0)" ::: "memory");
    asm volatile("s_barrier" ::: "memory");
#pragma unroll
    for (int m = 0; m < 4; ++m)
#pragma unroll
      for (int kk = 0; kk < 2; ++kk) af[m][kk] = rdA(m, kk, bk);
#pragma unroll
    for (int n = 0; n < 2; ++n)
#pragma unroll
      for (int kk = 0; kk < 2; ++kk) bf[n][kk] = rdB(n, kk, bk);
    __builtin_amdgcn_s_setprio(1);
#pragma unroll
    for (int m = 0; m < 4; ++m)
#pragma unroll
      for (int n = 0; n < 2; ++n)
#pragma unroll
        for (int kk = 0; kk < 2; ++kk)
          acc[m][n] = __builtin_amdgcn_mfma_f32_16x16x32_f16(af[m][kk], bf[n][kk], acc[m][n], 0, 0, 0);
    __builtin_amdgcn_s_setprio(0);
    asm volatile("s_barrier" ::: "memory");

#pragma unroll
    for (int n = 2; n < 4; ++n)
#pragma unroll
      for (int kk = 0; kk < 2; ++kk) bf[n][kk] = rdB(n, kk, bk);
    if (pf) stage(2, kt + 1, nb2);
    asm volatile("s_barrier" ::: "memory");
    __builtin_amdgcn_s_setprio(1);
#pragma unroll
    for (int m = 0; m < 4; ++m)
#pragma unroll
      for (int n = 2; n < 4; ++n)
#pragma unroll
        for (int kk = 0; kk < 2; ++kk)
          acc[m][n] = __builtin_amdgcn_mfma_f32_16x16x32_f16(af[m][kk], bf[n][kk], acc[m][n], 0, 0, 0);
    __builtin_amdgcn_s_setprio(0);
    asm volatile("s_barrier" ::: "memory");

#pragma unroll
    for (int m = 0; m < 4; ++m)
#pragma unroll
      for (int kk = 0; kk < 2; ++kk) af[m][kk] = rdA(m + 4, kk, bk);
    if (pf) stage(3, kt + 1, nb2);
    asm volatile("s_barrier" ::: "memory");
    __builtin_amdgcn_s_setprio(1);
#pragma unroll
    for (int m = 0; m < 4; ++m)
#pragma unroll
      for (int n = 2; n < 4; ++n)
#pragma unroll
        for (int kk = 0; kk < 2; ++kk)
          acc[m + 4][n] = __builtin_amdgcn_mfma_f32_16x16x32_f16(af[m][kk], bf[n][kk], acc[m + 4][n], 0, 0, 0);
    __builtin_amdgcn_s_setprio(0);
    asm volatile("s_barrier" ::: "memory");

    asm volatile("s_barrier" ::: "memory");
    __builtin_amdgcn_s_setprio(1);
#pragma unroll
    for (int m = 0; m < 4; ++m)
#pragma unroll
      for (int n = 0; n < 2; ++n)
#pragma unroll
        for (int kk = 0; kk < 2; ++kk)
          acc[m + 4][n] = __builtin_amdgcn_mfma_f32_16x16x32_f16(af[m][kk], bf[n][kk], acc[m + 4][n], 0, 0, 0);
    __builtin_amdgcn_s_setprio(0);
    asm volatile("s_barrier" ::: "memory");
  }
}

// -------- fused QKV projection: 240 blocks = 160 Q + 40 K + 40 V ---------
__global__ __launch_bounds__(512) void fused_qkv(const __half* __restrict__ X,
                                                 const __half* __restrict__ L,
                                                 const __half* __restrict__ Wq,
                                                 const __half* __restrict__ Wk,
                                                 const __half* __restrict__ Wv,
                                                 __half* __restrict__ Qa,
                                                 __half* __restrict__ Ka,
                                                 __half* __restrict__ Va) {
  __shared__ __half smem[2 * 32768];
  int wg = blockIdx.x;                       // 240 = 8 XCD * 30
  wg = (wg & 7) * 30 + (wg >> 3);            // bijective XCD swizzle

  int mode, bm, bn;
  const __half *A, *B;
  if (wg < 160)      { mode = 0; A = X; B = Wq; bm = wg / 10;        bn = wg - bm * 10; }
  else if (wg < 200) { mode = 1; A = L; B = Wk; bm = (wg - 160) / 10; bn = (wg - 160) - bm * 10; }
  else               { mode = 2; A = L; B = Wv; bm = (wg - 200) / 10; bn = (wg - 200) - bm * 10; }

  f32x4_t acc[8][4] = {};
  gemm256_core(A, B, bm, bn, smem, acc);

  const int lane = threadIdx.x & 63, wave = threadIdx.x >> 6;
  const int wr = wave >> 2, wc = wave & 3;
  const int fr = lane & 15, kb = lane >> 4;

#pragma unroll
  for (int m = 0; m < 8; ++m)
#pragma unroll
    for (int n = 0; n < 4; ++n)
#pragma unroll
      for (int r = 0; r < 4; ++r) {
        const int row = bm * 256 + wr * 128 + m * 16 + kb * 4 + r;
        const int col = bn * 256 + wc * 64 + n * 16 + fr;
        const float v = acc[m][n][r];
        const int h = col / DHD, d = col - h * DHD;
        if (mode == 0) {
          const int b = row >> 11, s = row & 2047;
          Qa[(((size_t)(b * NH + h)) * NS + s) * DHP + d] =
              __float2half(v * 0.11180339887498949f);     // 1/sqrt(80) folded
        } else if (mode == 1) {
          const int b = row >> 9, l = row & 511;
          Ka[(((size_t)(b * NH + h)) * NL + l) * DHP + d] = __float2half(v);
        } else {
          const int b = row >> 9, l = row & 511;
          Va[(((size_t)(b * NH + h)) * DHP + d) * NL + l] = __float2half(v);
        }
      }
}

// ==== O projection: 256x160 tile, 4Mx2N waves, 256 blocks = 100% fill ====
// out = gate * (AO x Wo^T), fp32. Same T2/T3/T4/T5 schedule as gemm256.
// LDS/bank: A 256x64 (32KB) + B 160x64 (20KB) = 52KB; 2 banks = 104KB.
// Staging/wave/K-step: 4 A-loads @ph0, 2 B @ph1, 1 B @ph2 (waves 0-3 only);
// vmcnt(4) at ph0 drains previous tile's 6-7 loads, keeps 4 fresh in flight.
__global__ __launch_bounds__(512) void gemm160_o(const __half* __restrict__ A,
                                                 const __half* __restrict__ Bt,
                                                 float* __restrict__ out,
                                                 const float* __restrict__ gate_p) {
  __shared__ __half smem[2 * 26624];         // per bank: A 16384 + B 10240 halfs
  const int K = HID;
  int wg = blockIdx.x;                       // 256 = 8 XCD * 32
  wg = (wg & 7) * 32 + (wg >> 3);
  const int bm = wg >> 4, bn = wg & 15;      // 16 x 16

  const int tid  = threadIdx.x;
  const int lane = tid & 63;
  const int wave = tid >> 6;
  const int wr = wave >> 1, wc = wave & 1;   // 4M x 2N
  const int fr = lane & 15, kb = lane >> 4;

  const int sr = tid >> 3;
  const int sj = (tid & 7) ^ (sr & 7);
  const __half* gA = A + (size_t)(bm * 256 + sr) * K + sj * 8;

  auto stageA = [&](int h, int kt, int bank) {   // h=0: rows 0-127, h=1: 128-255
    const int rbase = h * 128;
#pragma unroll
    for (int i = 0; i < 2; ++i) {
      const __half* g = gA + (size_t)(rbase + i * 64) * K + (size_t)kt * 64;
      __half* l = smem + bank * 26624 + (rbase + i * 64) * 64 + tid * 8;
      gload_lds16(g, l);
    }
  };
  auto stageB = [&](int c, int kt, int bank) {   // c=0,1: 512 slots; c=2: 256
    if (c < 2 || tid < 256) {
      const int s = c * 512 + tid;
      const int row = s >> 3;
      const int j = (tid & 7) ^ (row & 7);
      const __half* g = Bt + (size_t)(bn * 160 + row) * K + (size_t)kt * 64 + j * 8;
      __half* l = smem + bank * 26624 + 16384 + s * 8;
      gload_lds16(g, l);
    }
  };
  auto rdA = [&](int m, int kk, int bank) -> half8_t {
    const int row = wr * 64 + m * 16 + fr;
    const int off = row * 128 + ((kk * 64 + kb * 16) ^ ((fr & 7) << 4));
    return *(const half8_t*)((const char*)(smem + bank * 26624) + off);
  };
  auto rdB = [&](int n, int kk, int bank) -> half8_t {
    const int row = wc * 80 + n * 16 + fr;
    const int off = row * 128 + ((kk * 64 + kb * 16) ^ ((fr & 7) << 4));
    return *(const half8_t*)((const char*)(smem + bank * 26624 + 16384) + off);
  };

  f32x4_t acc[4][5] = {};
  half8_t af[2][2], bf[5][2];

  // prologue: full tile kt=0 into bank 0 (6-7 loads/wave in flight)
  stageA(0, 0, 0); stageA(1, 0, 0);
  stageB(0, 0, 0); stageB(1, 0, 0); stageB(2, 0, 0);

  const int nk = K >> 6;
  for (int kt = 0; kt < nk; ++kt) {
    const int bk = kt & 1, nb2 = bk ^ 1;
    const bool pf = (kt + 1 < nk);

    // ---- phase 0: (m0-1, n0-2); issue A half-tiles of kt+1
    if (pf) { stageA(0, kt + 1, nb2); stageA(1, kt + 1, nb2); }
    if (pf) asm volatile("s_waitcnt vmcnt(4)" ::: "memory");
    else    asm volatile("s_waitcnt vmcnt(0)" ::: "memory");
    asm volatile("s_barrier" ::: "memory");
#pragma unroll
    for (int m = 0; m < 2; ++m)
#pragma unroll
      for (int kk = 0; kk < 2; ++kk) af[m][kk] = rdA(m, kk, bk);
#pragma unroll
    for (int n = 0; n < 3; ++n)
#pragma unroll
      for (int kk = 0; kk < 2; ++kk) bf[n][kk] = rdB(n, kk, bk);
    __builtin_amdgcn_s_setprio(1);
#pragma unroll
    for (int m = 0; m < 2; ++m)
#pragma unroll
      for (int n = 0; n < 3; ++n)
#pragma unroll
        for (int kk = 0; kk < 2; ++kk)
          acc[m][n] = __builtin_amdgcn_mfma_f32_16x16x32_f16(af[m][kk], bf[n][kk], acc[m][n], 0, 0, 0);
    __builtin_amdgcn_s_setprio(0);
    asm volatile("s_barrier" ::: "memory");

    // ---- phase 1: (m0-1, n3-4); issue B chunks 0-1 of kt+1
#pragma unroll
    for (int n = 3; n < 5; ++n)
#pragma unroll
      for (int kk = 0; kk < 2; ++kk) bf[n][kk] = rdB(n, kk, bk);
    if (pf) { stageB(0, kt + 1, nb2); stageB(1, kt + 1, nb2); }
    asm volatile("s_barrier" ::: "memory");
    __builtin_amdgcn_s_setprio(1);
#pragma unroll
    for (int m = 0; m < 2; ++m)
#pragma unroll
      for (int n = 3; n < 5; ++n)
#pragma unroll
        for (int kk = 0; kk < 2; ++kk)
          acc[m][n] = __builtin_amdgcn_mfma_f32_16x16x32_f16(af[m][kk], bf[n][kk], acc[m][n], 0, 0, 0);
    __builtin_amdgcn_s_setprio(0);
    asm volatile("s_barrier" ::: "memory");

    // ---- phase 2: (m2-3, n3-4); issue B chunk 2 of kt+1
#pragma unroll
    for (int m = 0; m < 2; ++m)
#pragma unroll
      for (int kk = 0; kk < 2; ++kk) af[m][kk] = rdA(m + 2, kk, bk);
    if (pf) stageB(2, kt + 1, nb2);
    asm volatile("s_barrier" ::: "memory");
    __builtin_amdgcn_s_setprio(1);
#pragma unroll
    for (int m = 0; m < 2; ++m)
#pragma unroll
      for (int n = 3; n < 5; ++n)
#pragma unroll
        for (int kk = 0; kk < 2; ++kk)
          acc[m + 2][n] = __builtin_amdgcn_mfma_f32_16x16x32_f16(af[m][kk], bf[n][kk], acc[m + 2][n], 0, 0, 0);
    __builtin_amdgcn_s_setprio(0);
    asm volatile("s_barrier" ::: "memory");

    // ---- phase 3: (m2-3, n0-2); no staging
    asm volatile("s_barrier" ::: "memory");
    __builtin_amdgcn_s_setprio(1);
#pragma unroll
    for (int m = 0; m < 2; ++m)
#pragma unroll
      for (int n = 0; n < 3; ++n)
#pragma unroll
        for (int kk = 0; kk < 2; ++kk)
          acc[m + 2][n] = __builtin_amdgcn_mfma_f32_16x16x32_f16(af[m][kk], bf[n][kk], acc[m + 2][n], 0, 0, 0);
    __builtin_amdgcn_s_setprio(0);
    asm volatile("s_barrier" ::: "memory");
  }

  const float gate = tanhf(gate_p[0]);
#pragma unroll
  for (int m = 0; m < 4; ++m)
#pragma unroll
    for (int n = 0; n < 5; ++n)
#pragma unroll
      for (int r = 0; r < 4; ++r) {
        const int row = bm * 256 + wr * 64 + m * 16 + kb * 4 + r;
        const int col = bn * 160 + wc * 80 + n * 16 + fr;
        __builtin_nontemporal_store(gate * acc[m][n][r],
                                    &out[(size_t)row * HID + col]);
      }
}

// ------- attention: K/V staged per-block in LDS (64-key chunks) ----------
__global__ __launch_bounds__(256, 2) void attn_kernel(const __half* __restrict__ Q,
                                                      const __half* __restrict__ Kt,
                                                      const __half* __restrict__ Vt,
                                                      float* __restrict__ P,
                                                      __half* __restrict__ AO) {
  __shared__ __half Pl[4 * 16 * 520];
  __shared__ __half KV[6144];
  const int tid = threadIdx.x;
  const int lane = tid & 63, wave = tid >> 6;
  const int fr = lane & 15, kb = lane >> 4;
  const int bh = blockIdx.y;
  const int r0 = blockIdx.x * 64 + wave * 16;

  const __half* Qb = Q  + ((size_t)bh * NS + r0) * DHP;
  const __half* Kb = Kt + (size_t)bh * NL * DHP;
  const __half* Vb = Vt + (size_t)bh * DHP * NL;

  half8_t aq[3];
#pragma unroll
  for (int kk = 0; kk < 3; ++kk)
    aq[kk] = *(const half8_t*)(Qb + (size_t)fr * DHP + kk * 32 + kb * 8);

  f32x4_t scr[32];

  for (int c = 0; c < 8; ++c) {
#pragma unroll
    for (int i = 0; i < 3; ++i) {
      const int s = (wave * 3 + i) * 64 + lane;
      gload_lds16(Kb + (size_t)c * 64 * DHP + s * 8, KV + s * 8);
    }
    __syncthreads();
#pragma unroll
    for (int ntl = 0; ntl < 4; ++ntl) {
      f32x4_t a = {};
#pragma unroll
      for (int kk = 0; kk < 3; ++kk) {
        half8_t bfv = *(const half8_t*)(KV + (ntl * 16 + fr) * DHP + kk * 32 + kb * 8);
        a = __builtin_amdgcn_mfma_f32_16x16x32_f16(aq[kk], bfv, a, 0, 0, 0);
      }
      scr[c * 4 + ntl] = a;
    }
    __syncthreads();
  }

#pragma unroll
  for (int i = 0; i < 3; ++i) {
    const int s = (wave * 3 + i) * 64 + lane;
    int row = s / 9;
    int col = s - row * 9;
    if (row > 79) row = 79;
    if (col > 7) col = 7;
    gload_lds16(Vb + (size_t)row * NL + col * 8, KV + s * 8);
  }

  __half* Plw = Pl + wave * (16 * 520);
#pragma unroll
  for (int r = 0; r < 4; ++r) {
    float m = -1e30f;
#pragma unroll
    for (int nt = 0; nt < 32; ++nt) m = fmaxf(m, scr[nt][r]);
#pragma unroll
    for (int d = 1; d < 16; d <<= 1) m = fmaxf(m, __shfl_xor(m, d));
    float s = 0.f;
#pragma unroll
    for (int nt = 0; nt < 32; ++nt) {
      float p = __expf(scr[nt][r] - m);
      scr[nt][r] = p;
      s += p;
    }
#pragma unroll
    for (int d = 1; d < 16; d <<= 1) s += __shfl_xor(s, d);
    const float iv = 1.f / s;
#pragma unroll
    for (int nt = 0; nt < 32; ++nt) {
      float p = scr[nt][r] * iv;
      scr[nt][r] = p;
      Plw[(kb * 4 + r) * 520 + nt * 16 + fr] = __float2half(p);
    }
  }

  f32x4_t oc[5] = {};
  for (int c = 0; c < 8; ++c) {
    if (c > 0) {
#pragma unroll
      for (int i = 0; i < 3; ++i) {
        const int s = (wave * 3 + i) * 64 + lane;
        int row = s / 9;
        int col = s - row * 9;
        if (row > 79) row = 79;
        if (col > 7) col = 7;
        gload_lds16(Vb + (size_t)row * NL + c * 64 + col * 8, KV + s * 8);
      }
    }
    __syncthreads();
#pragma unroll
    for (int k0l = 0; k0l < 2; ++k0l) {
      half8_t ap = *(const half8_t*)(Plw + fr * 520 + (c * 2 + k0l) * 32 + kb * 8);
#pragma unroll
      for (int n = 0; n < 5; ++n) {
        half8_t bv = *(const half8_t*)(KV + (n * 16 + fr) * 72 + k0l * 32 + kb * 8);
        oc[n] = __builtin_amdgcn_mfma_f32_16x16x32_f16(ap, bv, oc[n], 0, 0, 0);
      }
    }
    __syncthreads();
  }

  const int b = bh >> 5, h = bh & 31;
#pragma unroll
  for (int n = 0; n < 5; ++n)
#pragma unroll
    for (int r = 0; r < 4; ++r) {
      const int srow = r0 + kb * 4 + r;
      AO[((size_t)b * NS + srow) * HID + h * DHD + n * 16 + fr] = __float2half(oc[n][r]);
    }
#pragma unroll
  for (int r = 0; r < 4; ++r) {
    const int srow = r0 + kb * 4 + r;
    float* Pr = P + ((size_t)bh * NS + srow) * NL;
#pragma unroll
    for (int nt = 0; nt < 32; ++nt)
      __builtin_nontemporal_store(scr[nt][r], &Pr[nt * 16 + fr]);
  }
}

extern "C" void kernel_launch(void* const* d_in, const int* in_sizes, int n_in,
                              void* d_out, int out_size, void* d_ws, size_t ws_size,
                              hipStream_t stream) {
  const float* X  = (const float*)d_in[0];
  const float* LS = (const float*)d_in[1];
  const float* Wq = (const float*)d_in[2];
  const float* Wk = (const float*)d_in[3];
  const float* Wv = (const float*)d_in[4];
  const float* Wo = (const float*)d_in[5];
  const float* gp = (const float*)d_in[6];
  float* out  = (float*)d_out;
  float* Pout = out + (size_t)NB * NS * HID;

  char* w = (char*)d_ws;
  auto alloc = [&](size_t bytes) {
    char* p = w;
    w += (bytes + 255) & ~(size_t)255;
    return p;
  };
  __half* Xh  = (__half*)alloc((size_t)NB * NS * HID * 2);
  __half* Lh  = (__half*)alloc((size_t)NB * NL * HID * 2);
  __half* Wqh = (__half*)alloc((size_t)HID * HID * 2);
  __half* Wkh = (__half*)alloc((size_t)HID * HID * 2);
  __half* Wvh = (__half*)alloc((size_t)HID * HID * 2);
  __half* Woh = (__half*)alloc((size_t)HID * HID * 2);
  __half* Qa  = (__half*)alloc((size_t)NB * NH * NS * DHP * 2);
  __half* Ka  = (__half*)alloc((size_t)NB * NH * NL * DHP * 2);
  __half* Va  = (__half*)alloc((size_t)NB * NH * DHP * NL * 2);
  (void)alloc(4096);                     // guard region after Va
  __half* AOh = Xh;  // Xh dead after QKV projection

  cast_all<<<dim3(2048), dim3(256), 0, stream>>>(X, LS, Wq, Wk, Wv, Wo,
                                                 Xh, Lh, Wqh, Wkh, Wvh, Woh,
                                                 Qa, Ka);
  fused_qkv<<<dim3(240), dim3(512), 0, stream>>>(Xh, Lh, Wqh, Wkh, Wvh, Qa, Ka, Va);
  attn_kernel<<<dim3(NS / 64, NB * NH), dim3(256), 0, stream>>>(
      Qa, Ka, Va, Pout, AOh);
  gemm160_o<<<dim3(256), dim3(512), 0, stream>>>(AOh, Woh, out, gp);
}